// Round 13
// baseline (221.711 us; speedup 1.0000x reference)
//
#include <hip/hip_runtime.h>

constexpr int N_ = 4096, C_ = 32, CN_ = 64, M_ = 64;
constexpr int TPB = 256;              // fps block: 4 waves, 1/SIMD, 512-reg budget
constexpr int RPT = 13, LPT = 3;      // reg / LDS points per thread
constexpr int NREG = RPT * TPB;       // 3328
constexpr int NLDS = N_ - NREG;       // 768
constexpr int NWAVES = TPB / 64;      // 4
constexpr int NTPB = 256;             // norms block
constexpr int NCHUNK = N_ / NTPB;     // 16

typedef float v2f  __attribute__((ext_vector_type(2)));
typedef float v16f __attribute__((ext_vector_type(16)));

// packed f32 FMA: acc.{lo,hi} += z.{lo,hi} * c.{lo,hi}; c is an SGPR pair
#define PKFMA(acc, zz, cc) \
  asm("v_pk_fma_f32 %0, %1, %2, %0" : "+v"(acc) : "v"(zz), "s"(cc))

// monotone f32 -> u32 map (total order preserved incl. negatives)
__device__ __forceinline__ unsigned fmap(float v) {
  unsigned u = __float_as_uint(v);
  u ^= (unsigned)((int)u >> 31) | 0x80000000u;
  return u;
}

// force a wave-uniform float into an SGPR
__device__ __forceinline__ float rfl(float v) {
  return __uint_as_float(__builtin_amdgcn_readfirstlane(__float_as_uint(v)));
}

// one DPP max-combine stage on a packed u64 key (VALU pipe — no LDS traffic).
template <int CTRL, int RM>
__device__ __forceinline__ unsigned long long kmax_dpp(unsigned long long k) {
  int lo = (int)(unsigned)k, hi = (int)(unsigned)(k >> 32);
  int plo = __builtin_amdgcn_update_dpp(lo, lo, CTRL, RM, 0xf, false);
  int phi = __builtin_amdgcn_update_dpp(hi, hi, CTRL, RM, 0xf, false);
  unsigned long long p =
      ((unsigned long long)(unsigned)phi << 32) | (unsigned)plo;
  return p > k ? p : k;
}

// full-wave max of packed key; lane 63 holds it.
__device__ __forceinline__ unsigned long long wave_kmax(unsigned long long k) {
  k = kmax_dpp<0x111, 0xF>(k);   // row_shr:1
  k = kmax_dpp<0x112, 0xF>(k);   // row_shr:2
  k = kmax_dpp<0x114, 0xF>(k);   // row_shr:4
  k = kmax_dpp<0x118, 0xF>(k);   // row_shr:8
  k = kmax_dpp<0x142, 0xA>(k);   // row_bcast:15 -> rows 1,3
  k = kmax_dpp<0x143, 0xC>(k);   // row_bcast:31 -> rows 2,3
  return k;
}

// ---------------- kernel 0: per-point z = G·x (f64 accum) + norms + Σx partials ----------------
// blk = (b*3+r)*16 + chunk ; r=0: G=I, r=1: G=Wk^T Wk, r=2: G=Wv^T Wv
__global__ __attribute__((amdgpu_flat_work_group_size(NTPB, NTPB),
                          amdgpu_waves_per_eu(1, 4)))
void norms_kernel(
    const float* __restrict__ ev, const float* __restrict__ Wk,
    const float* __restrict__ Wv, float* __restrict__ nrm_all,
    float* __restrict__ zall, float* __restrict__ partials) {
  int blk = blockIdx.x;
  int chunk = blk & (NCHUNK - 1), br = blk >> 4;
  int r = br % 3, b = br / 3;
  int t = threadIdx.x;
  __shared__ float G[C_][C_ + 1];
  const float* W = (r == 1) ? Wk : Wv;
  for (int e = t; e < C_ * C_; e += NTPB) {
    int a = e >> 5, d = e & 31;
    float g;
    if (r == 0) {
      g = (a == d) ? 1.f : 0.f;
    } else {
      double acc = 0.0;
      for (int q = 0; q < CN_; ++q)
        acc += (double)W[q * C_ + a] * (double)W[q * C_ + d];
      g = (float)acc;
    }
    G[a][d] = g;
  }
  __syncthreads();
  int p = chunk * NTPB + t;
  const float4* row = (const float4*)(ev + ((size_t)b * N_ + p) * C_);
  float x[C_];
#pragma unroll
  for (int q = 0; q < C_ / 4; ++q) {
    float4 v = row[q];
    x[q * 4 + 0] = v.x; x[q * 4 + 1] = v.y; x[q * 4 + 2] = v.z; x[q * 4 + 3] = v.w;
  }
  double n = 0.0;
  float z[C_];
#pragma unroll
  for (int a = 0; a < C_; ++a) {
    double ta = 0.0;
#pragma unroll
    for (int d = 0; d < C_; ++d) ta += (double)G[a][d] * (double)x[d];
    z[a] = (float)ta;
    n += ta * (double)x[a];
  }
  nrm_all[(size_t)br * N_ + p] = (float)n;
  float4* zrow = (float4*)(zall + ((size_t)br * N_ + p) * C_);
#pragma unroll
  for (int q = 0; q < C_ / 4; ++q)
    zrow[q] = make_float4(z[q * 4 + 0], z[q * 4 + 1], z[q * 4 + 2], z[q * 4 + 3]);

  if (r == 0) {   // deterministic per-chunk Σx partials (no atomics)
    __shared__ float msum[NTPB / 64][C_];
#pragma unroll
    for (int d = 0; d < C_; ++d) {
      float s = x[d];
#pragma unroll
      for (int off = 32; off; off >>= 1) s += __shfl_xor(s, off);
      if ((t & 63) == 0) msum[t >> 6][d] = s;
    }
    __syncthreads();
    if (t < C_)
      partials[((size_t)b * NCHUNK + chunk) * C_ + t] =
          msum[0][t] + msum[1][t] + msum[2][t] + msum[3][t];
  }
}

// ---------------- kernel 1: FPS — one block per (batch,run), z-metric ----------------
// d(i, sel) = n_i - 2 * z_i · x_sel + n_sel    (G symmetric: x_i·G·c = z_i·c)
// 256 threads, 1 wave/SIMD, waves_per_eu(1,1) -> 512-reg budget: 13 points/thread
// in registers (z=416 regs), only 768 points in LDS -> 96 ds_read_b128/iter.
__global__ __attribute__((amdgpu_flat_work_group_size(TPB, TPB),
                          amdgpu_waves_per_eu(1, 1)))
void fps_kernel(
    const float* __restrict__ ev, const float* __restrict__ nrm_all,
    const float* __restrict__ zall, const float* __restrict__ partials,
    int* __restrict__ idx_ws) {
  const int t = threadIdx.x;
  const int blk = blockIdx.x;          // b*3 + r
  const int b = blk / 3;
  const float* evb = ev + (size_t)b * N_ * C_;
  const float* nrm = nrm_all + (size_t)blk * N_;
  const float4* zb4 = (const float4*)(zall + (size_t)blk * N_ * C_);

  __shared__ float LP[C_ / 4][NLDS][4];   // [q][col][4] — conflict-free b128 (96 KB)
  __shared__ float cf0[C_];               // barycenter (round 0 only)
  __shared__ unsigned long long redK[2][NWAVES];

  v2f z2[RPT][C_ / 2];
  float pn[RPT], dmin[RPT];
  float nl[LPT], dminL[LPT];

  // ---- load reg z-points (as VGPR pairs for v_pk_fma_f32) ----
#pragma unroll
  for (int j = 0; j < RPT; ++j) {
    int p = j * TPB + t;
#pragma unroll
    for (int q = 0; q < C_ / 4; ++q) {
      float4 v = zb4[(size_t)p * 8 + q];
      z2[j][2 * q + 0] = v2f{v.x, v.y};
      z2[j][2 * q + 1] = v2f{v.z, v.w};
    }
    pn[j] = nrm[p];
    dmin[j] = 1e10f;
  }
  // ---- stage LDS z-points (3 per thread), [q][col] layout ----
#pragma unroll
  for (int i = 0; i < LPT; ++i) {
    int col = i * TPB + t;
    int p = NREG + col;
#pragma unroll
    for (int q = 0; q < C_ / 4; ++q) {
      float4 v = zb4[(size_t)p * 8 + q];
      *(float4*)&LP[q][col][0] = v;
    }
    nl[i] = nrm[p];
    dminL[i] = 1e10f;
  }
  // ---- barycenter from partials (deterministic) ----
  if (t < C_) {
    float s = 0.f;
#pragma unroll
    for (int c = 0; c < NCHUNK; ++c) s += partials[((size_t)b * NCHUNK + c) * C_ + t];
    cf0[t] = s * (1.f / (float)N_);
  }
  __syncthreads();   // LP + cf0 ready

  // csp[] pairs are SGPR-resident. Returns wave-reduced packed key
  // (fmap(best_v) << 12) | (4095 - best_idx) via DPP (no LDS ops).
  auto eval = [&](const v2f (&csp)[C_ / 2], float curN,
                  bool update) -> unsigned long long {
    v2f a[RPT], aL[LPT];
#pragma unroll
    for (int j = 0; j < RPT; ++j) a[j] = v2f{0.f, 0.f};
#pragma unroll
    for (int i = 0; i < LPT; ++i) aL[i] = v2f{0.f, 0.f};
#pragma unroll
    for (int q = 0; q < C_ / 4; ++q) {
#pragma unroll
      for (int i = 0; i < LPT; ++i) {
        float4 l = *(const float4*)&LP[q][i * TPB + t][0];
        v2f l0 = {l.x, l.y}, l1 = {l.z, l.w};
        PKFMA(aL[i], l0, csp[2 * q + 0]);
        PKFMA(aL[i], l1, csp[2 * q + 1]);
      }
#pragma unroll
      for (int j = 0; j < RPT; ++j) {
        PKFMA(a[j], z2[j][2 * q + 0], csp[2 * q + 0]);
        PKFMA(a[j], z2[j][2 * q + 1], csp[2 * q + 1]);
      }
    }
    float bv = -3e38f; int bi = 0;
#pragma unroll
    for (int j = 0; j < RPT; ++j) {
      float d = fmaf(-2.f, a[j].x + a[j].y, pn[j]) + curN;
      float v;
      if (update) { dmin[j] = fminf(dmin[j], d); v = dmin[j]; }
      else v = d;
      if (v > bv) { bv = v; bi = j * TPB + t; }   // strict > keeps lowest index
    }
#pragma unroll
    for (int i = 0; i < LPT; ++i) {
      float d = fmaf(-2.f, aL[i].x + aL[i].y, nl[i]) + curN;
      float v;
      if (update) { dminL[i] = fminf(dminL[i], d); v = dminL[i]; }
      else v = d;
      if (v > bv) { bv = v; bi = NREG + i * TPB + t; }
    }
    unsigned long long k =
        ((unsigned long long)fmap(bv) << 12) | (unsigned)(4095 - bi);
    return wave_kmax(k);
  };

  // ---- round 0: barycenter (additive shift irrelevant for argmax; no dmin update) ----
  {
    v2f csp[C_ / 2];
#pragma unroll
    for (int i = 0; i < C_ / 2; ++i)
      csp[i] = v2f{rfl(cf0[2 * i]), rfl(cf0[2 * i + 1])};
    unsigned long long k = eval(csp, 0.f, false);
    if ((t & 63) == 63) redK[0][t >> 6] = k;
  }
  __syncthreads();

  // ---- main loop: 1 barrier/iter; cross-wave reduce over 4 entries =
  // 1 ds_read_b64 + 2 DPP stages + readlane; centroid on the SCALAR pipe ----
  for (int it = 0; it < M_; ++it) {
    int rb = it & 1;
    unsigned long long k = redK[rb][t & (NWAVES - 1)];
    k = kmax_dpp<0x111, 0xF>(k);
    k = kmax_dpp<0x112, 0xF>(k);
    unsigned klo = (unsigned)__builtin_amdgcn_readlane((int)(unsigned)k, 3);
    int jsel = 4095 - (int)(klo & 4095u);          // SGPR-uniform
    if (t == 0) idx_ws[blk * M_ + it] = jsel;
    // owner kills its dmin slot (never re-select) — static indices only
    if (jsel < NREG) {
      if ((jsel & (TPB - 1)) == t) {
        int j = jsel >> 8;
#pragma unroll
        for (int jj = 0; jj < RPT; ++jj)
          if (jj == j) dmin[jj] = -3e38f;
      }
    } else {
      int col = jsel - NREG;
      if ((col & (TPB - 1)) == t) {
        int i = col >> 8;
#pragma unroll
        for (int ii = 0; ii < LPT; ++ii)
          if (ii == i) dminL[ii] = -3e38f;
      }
    }
    if (it == M_ - 1) break;
    // scalar-pipe fetch of the selected point's 128B row + norm (uniform addr)
    const float* cfp = evb + (size_t)jsel * C_;
    const float* nrmp = nrm + jsel;
    v16f cs0, cs1; float curN;
    asm volatile(
        "s_load_dwordx16 %0, %3, 0\n\t"
        "s_load_dwordx16 %1, %3, 64\n\t"
        "s_load_dword %2, %4, 0\n\t"
        "s_waitcnt lgkmcnt(0)"
        : "=&s"(cs0), "=&s"(cs1), "=&s"(curN)
        : "s"(cfp), "s"(nrmp));
    v2f csp[C_ / 2];
#pragma unroll
    for (int i = 0; i < 8; ++i) {
      csp[i]     = v2f{cs0[2 * i], cs0[2 * i + 1]};
      csp[8 + i] = v2f{cs1[2 * i], cs1[2 * i + 1]};
    }
    unsigned long long kk = eval(csp, curN, true);
    if ((t & 63) == 63) redK[rb ^ 1][t >> 6] = kk;
    __syncthreads();
  }
}

// ---------------- kernel 2: finalize (256 threads per batch) ----------------
// fps() returns selections in ASCENDING ORIGINAL-INDEX order (masked_select);
// rank-sort each run's indices before zipping along m (pairing matters).
// PRJ[0]=pe (ev-run pts @ Wpe), PRJ[1]=km (k-run pts @ Wk), PRJ[2]=vm (v-run @ Wv).
__global__ __launch_bounds__(256, 1) void finalize_kernel(
    const float* __restrict__ ev, const float* __restrict__ Wk,
    const float* __restrict__ Wv, const float* __restrict__ Wpe,
    const float* __restrict__ Wsa1, const float* __restrict__ Wsa2,
    const int* __restrict__ idx_ws, const float* __restrict__ partials,
    float* __restrict__ outvec_ws) {
  const int b = blockIdx.x;
  const int t = threadIdx.x;           // 256 threads = 4 waves
  const float* evb = ev + (size_t)b * N_ * C_;

  __shared__ float Wl[3][CN_][C_];        // 24 KB: Wpe, Wk, Wv
  __shared__ float W1l[CN_];
  __shared__ float W2l[C_][CN_ + 1];      // padded: conflict-free per-lane rows
  __shared__ int   lidx[3][M_], sidx[3][M_];
  __shared__ float XP[3][M_][C_];         // 24 KB selected rows
  __shared__ float PRJ[3][M_][CN_ + 1];   // padded
  __shared__ float sumx[C_], Pl[CN_], sl[M_], TP[4][CN_];

  // ---- stage weights ----
  {
    const float* Ws[3] = {Wpe, Wk, Wv};
#pragma unroll
    for (int r = 0; r < 3; ++r)
      for (int i = t; i < CN_ * C_ / 4; i += 256)
        ((float4*)&Wl[r][0][0])[i] = ((const float4*)Ws[r])[i];
    if (t < CN_) W1l[t] = Wsa1[t];
    for (int i = t; i < C_ * CN_; i += 256)
      W2l[i >> 6][i & 63] = Wsa2[i];      // scalar (padded dest not f4-aligned)
  }
  if (t < 192) {
    int r = t >> 6, mm = t & 63;
    lidx[r][mm] = idx_ws[(b * 3 + r) * M_ + mm];
  }
  if (t < C_) {
    float s = 0.f;
#pragma unroll
    for (int c = 0; c < NCHUNK; ++c) s += partials[((size_t)b * NCHUNK + c) * C_ + t];
    sumx[t] = s;
  }
  __syncthreads();
  if (t < 192) {       // parallel rank-sort: 3 runs × 64 slots
    int r = t >> 6, mm = t & 63;
    int my = lidx[r][mm];
    int rank = 0;
#pragma unroll
    for (int j = 0; j < M_; ++j)
      rank += (lidx[r][j] < my) || (lidx[r][j] == my && j < mm);
    sidx[r][rank] = my;
  }
  __syncthreads();
  // ---- stage selected rows: 192 rows × 8 quads ----
  for (int g = t; g < 3 * M_ * 8; g += 256) {
    int row = g >> 3, q = g & 7;
    int r = row >> 6, m = row & 63;
    int pi = sidx[r][m];
    *(float4*)&XP[r][m][q * 4] = ((const float4*)(evb + (size_t)pi * C_))[q];
  }
  __syncthreads();
  // ---- projections: wave r handles run r (lane = cn, W row in regs, x broadcast) ----
  {
    int w = t >> 6, cn = t & 63;
    if (w < 3) {
      float wr[C_];
#pragma unroll
      for (int q = 0; q < C_ / 4; ++q) {
        float4 v = *(const float4*)&Wl[w][cn][q * 4];
        wr[q * 4 + 0] = v.x; wr[q * 4 + 1] = v.y;
        wr[q * 4 + 2] = v.z; wr[q * 4 + 3] = v.w;
      }
      for (int m = 0; m < M_; ++m) {
        float a = 0.f;
#pragma unroll
        for (int q = 0; q < C_ / 4; ++q) {
          float4 x = *(const float4*)&XP[w][m][q * 4];   // wave-broadcast read
          a = fmaf(x.x, wr[q * 4 + 0], a);
          a = fmaf(x.y, wr[q * 4 + 1], a);
          a = fmaf(x.z, wr[q * 4 + 2], a);
          a = fmaf(x.w, wr[q * 4 + 3], a);
        }
        PRJ[w][m][cn] = a;
      }
    } else {
      // Pl[cn] = (Σ_n ev) @ Wpe^T
      float a = 0.f;
#pragma unroll
      for (int c = 0; c < C_; ++c) a = fmaf(sumx[c], Wl[0][cn][c], a);
      Pl[cn] = a;
    }
  }
  __syncthreads();
  // ---- logits + softmax: wave 0, lane m ----
  if (t < 64) {
    float cm = 0.f;
#pragma unroll 8
    for (int cn = 0; cn < CN_; ++cn)
      cm = fmaf(PRJ[1][t][cn] + PRJ[0][t][cn], W1l[cn], cm);
    float lg = -cm;
    float mx = lg;
#pragma unroll
    for (int off = 32; off; off >>= 1) mx = fmaxf(mx, __shfl_xor(mx, off));
    float e = expf(lg - mx);
    float ssum = e;
#pragma unroll
    for (int off = 32; off; off >>= 1) ssum += __shfl_xor(ssum, off);
    sl[t] = e / ssum;
  }
  __syncthreads();
  // ---- tvec partials: thread (cn = t&63, quarter h = t>>6) ----
  {
    int cn = t & 63, h = t >> 6;
    float a = 0.f;
#pragma unroll
    for (int i = 0; i < 16; ++i) {
      int mm = h * 16 + i;
      a = fmaf(sl[mm],
               fmaf((float)N_, PRJ[2][mm][cn], Pl[cn]) - (float)N_ * PRJ[0][mm][cn],
               a);
    }
    TP[h][cn] = a;
  }
  __syncthreads();
  if (t < C_) {
    float o = 0.f;
#pragma unroll 8
    for (int cn = 0; cn < CN_; ++cn) {
      float tv = TP[0][cn] + TP[1][cn] + TP[2][cn] + TP[3][cn];
      o = fmaf(tv, W2l[t][cn], o);
    }
    outvec_ws[b * C_ + t] = o;
  }
}

// ---------------- kernel 3: broadcast out[b][n][:] = outvec[b][:] ----------------
__global__ void bcast_kernel(const float* __restrict__ outvec_ws,
                             float4* __restrict__ out) {
  int i = blockIdx.x * 256 + threadIdx.x;   // < 4*4096*8
  int b = i >> 15;
  int j = i & 7;
  const float4* ov = (const float4*)outvec_ws;
  out[i] = ov[b * 8 + j];
}

extern "C" void kernel_launch(void* const* d_in, const int* in_sizes, int n_in,
                              void* d_out, int out_size, void* d_ws, size_t ws_size,
                              hipStream_t stream) {
  const float* ev   = (const float*)d_in[0];
  // d_in[1] = W_qs: provably unused (a_n cancels in softmax over m)
  const float* Wk   = (const float*)d_in[2];
  const float* Wv   = (const float*)d_in[3];
  const float* Wpe  = (const float*)d_in[4];
  const float* Wsa1 = (const float*)d_in[5];
  const float* Wsa2 = (const float*)d_in[6];
  float* out = (float*)d_out;

  char* ws = (char*)d_ws;
  int*   idx    = (int*)ws;                     // 12*64*4        = 3072 B
  float* parts  = (float*)(ws + 3072);          // 4*16*32*4      = 8192 B
  float* outvec = (float*)(ws + 11264);         // 4*32*4         = 512 B
  float* nrm    = (float*)(ws + 11776);         // 12*4096*4      = 196608 B
  float* zall   = (float*)(ws + 208384);        // 12*4096*32*4   = 6291456 B

  norms_kernel   <<<dim3(192), dim3(NTPB), 0, stream>>>(ev, Wk, Wv, nrm, zall, parts);
  fps_kernel     <<<dim3(12),  dim3(TPB),  0, stream>>>(ev, nrm, zall, parts, idx);
  finalize_kernel<<<dim3(4),   dim3(256),  0, stream>>>(ev, Wk, Wv, Wpe, Wsa1, Wsa2,
                                                        idx, parts, outvec);
  bcast_kernel   <<<dim3(512), dim3(256),  0, stream>>>(outvec, (float4*)out);
}

// Round 15
// 214.519 us; speedup vs baseline: 1.0335x; 1.0335x over previous
//
#include <hip/hip_runtime.h>

constexpr int N_ = 4096, C_ = 32, CN_ = 64, M_ = 64;
constexpr int NWG = 8;                // workgroups per FPS run
constexpr int SLICE = N_ / NWG;       // 512 points per WG
constexpr int TPB = 256;              // fps block: 4 waves; 2 points/thread in regs
constexpr int NTPB = 256;             // norms block
constexpr int NCHUNK = N_ / NTPB;     // 16

typedef float v2f  __attribute__((ext_vector_type(2)));
typedef float v16f __attribute__((ext_vector_type(16)));

// packed f32 FMA: acc.{lo,hi} += z.{lo,hi} * c.{lo,hi}; c is an SGPR pair
#define PKFMA(acc, zz, cc) \
  asm("v_pk_fma_f32 %0, %1, %2, %0" : "+v"(acc) : "v"(zz), "s"(cc))

// monotone f32 -> u32 map (total order preserved incl. negatives)
__device__ __forceinline__ unsigned fmap(float v) {
  unsigned u = __float_as_uint(v);
  u ^= (unsigned)((int)u >> 31) | 0x80000000u;
  return u;
}

// force a wave-uniform float into an SGPR
__device__ __forceinline__ float rfl(float v) {
  return __uint_as_float(__builtin_amdgcn_readfirstlane(__float_as_uint(v)));
}

// one DPP max-combine stage on a packed u64 key (VALU pipe — no LDS traffic).
template <int CTRL, int RM>
__device__ __forceinline__ unsigned long long kmax_dpp(unsigned long long k) {
  int lo = (int)(unsigned)k, hi = (int)(unsigned)(k >> 32);
  int plo = __builtin_amdgcn_update_dpp(lo, lo, CTRL, RM, 0xf, false);
  int phi = __builtin_amdgcn_update_dpp(hi, hi, CTRL, RM, 0xf, false);
  unsigned long long p =
      ((unsigned long long)(unsigned)phi << 32) | (unsigned)plo;
  return p > k ? p : k;
}

// full-wave max of packed key; lane 63 holds it.
__device__ __forceinline__ unsigned long long wave_kmax(unsigned long long k) {
  k = kmax_dpp<0x111, 0xF>(k);   // row_shr:1
  k = kmax_dpp<0x112, 0xF>(k);   // row_shr:2
  k = kmax_dpp<0x114, 0xF>(k);   // row_shr:4
  k = kmax_dpp<0x118, 0xF>(k);   // row_shr:8
  k = kmax_dpp<0x142, 0xA>(k);   // row_bcast:15 -> rows 1,3
  k = kmax_dpp<0x143, 0xC>(k);   // row_bcast:31 -> rows 2,3
  return k;
}

// ---------------- kernel 0: per-point z = G·x (f64 accum) + norms + Σx partials ----------------
// blk = (b*3+r)*16 + chunk ; r=0: G=I (z==x exactly -> zall row NOT stored;
// fps reads ev directly), r=1: G=Wk^T Wk, r=2: G=Wv^T Wv
__global__ __attribute__((amdgpu_flat_work_group_size(NTPB, NTPB),
                          amdgpu_waves_per_eu(1, 4)))
void norms_kernel(
    const float* __restrict__ ev, const float* __restrict__ Wk,
    const float* __restrict__ Wv, float* __restrict__ nrm_all,
    float* __restrict__ zall, float* __restrict__ partials) {
  int blk = blockIdx.x;
  int chunk = blk & (NCHUNK - 1), br = blk >> 4;
  int r = br % 3, b = br / 3;
  int t = threadIdx.x;
  __shared__ float G[C_][C_ + 1];
  const float* W = (r == 1) ? Wk : Wv;
  for (int e = t; e < C_ * C_; e += NTPB) {
    int a = e >> 5, d = e & 31;
    float g;
    if (r == 0) {
      g = (a == d) ? 1.f : 0.f;
    } else {
      double acc = 0.0;
      for (int q = 0; q < CN_; ++q)
        acc += (double)W[q * C_ + a] * (double)W[q * C_ + d];
      g = (float)acc;
    }
    G[a][d] = g;
  }
  __syncthreads();
  int p = chunk * NTPB + t;
  const float4* row = (const float4*)(ev + ((size_t)b * N_ + p) * C_);
  float x[C_];
#pragma unroll
  for (int q = 0; q < C_ / 4; ++q) {
    float4 v = row[q];
    x[q * 4 + 0] = v.x; x[q * 4 + 1] = v.y; x[q * 4 + 2] = v.z; x[q * 4 + 3] = v.w;
  }
  double n = 0.0;
  float z[C_];
#pragma unroll
  for (int a = 0; a < C_; ++a) {
    double ta = 0.0;
#pragma unroll
    for (int d = 0; d < C_; ++d) ta += (double)G[a][d] * (double)x[d];
    z[a] = (float)ta;
    n += ta * (double)x[a];
  }
  nrm_all[(size_t)br * N_ + p] = (float)n;
  if (r != 0) {   // r==0: z == x bit-exactly; fps reads ev instead
    float4* zrow =
        (float4*)(zall + ((size_t)(2 * b + r - 1) * N_ + p) * C_);
#pragma unroll
    for (int q = 0; q < C_ / 4; ++q)
      zrow[q] = make_float4(z[q * 4 + 0], z[q * 4 + 1], z[q * 4 + 2], z[q * 4 + 3]);
  }

  if (r == 0) {   // deterministic per-chunk Σx partials (no atomics)
    __shared__ float msum[NTPB / 64][C_];
#pragma unroll
    for (int d = 0; d < C_; ++d) {
      float s = x[d];
#pragma unroll
      for (int off = 32; off; off >>= 1) s += __shfl_xor(s, off);
      if ((t & 63) == 0) msum[t >> 6][d] = s;
    }
    __syncthreads();
    if (t < C_)
      partials[((size_t)b * NCHUNK + chunk) * C_ + t] =
          msum[0][t] + msum[1][t] + msum[2][t] + msum[3][t];
  }
}

// ---------------- kernel 1: FPS — 8 WGs per run; cross-WG combine via RMW atomics ----------------
// d(i, sel) = n_i - 2 * z_i · x_sel + n_sel    (G symmetric: x_i·G·c = z_i·c)
// Each WG holds its 512-point slice in registers (2 pts/thread). Per iteration:
// WG-local reduce -> atomicMax(slotK[s]) then atomicAdd(slotC[s]) [release] ->
// t0 spins slotC[s]==8 [acquire] -> load slotK[s] -> LDS broadcast.
// RMWs are performed at the device coherence point (no cross-XCD L2 staleness).
// Slots zeroed by hipMemsetAsync every launch.
__global__ __attribute__((amdgpu_flat_work_group_size(TPB, TPB),
                          amdgpu_waves_per_eu(1, 2)))
void fps_kernel(
    const float* __restrict__ ev, const float* __restrict__ nrm_all,
    const float* __restrict__ zall, const float* __restrict__ partials,
    int* __restrict__ idx_ws, unsigned long long* __restrict__ slotK,
    unsigned* __restrict__ slotC) {
  const int t = threadIdx.x;
  const int run = blockIdx.x >> 3;     // b*3 + r  (0..11)
  const int g = blockIdx.x & 7;        // slice id (0..7)
  const int b = run / 3, r = run % 3;
  const float* evb = ev + (size_t)b * N_ * C_;
  const float* nrm = nrm_all + (size_t)run * N_;
  const float4* zb4 = (r == 0)
      ? (const float4*)evb
      : (const float4*)(zall + (size_t)(2 * b + r - 1) * N_ * C_);
  unsigned long long* sK = slotK + (size_t)run * M_;
  unsigned* sC = slotC + (size_t)run * M_;

  __shared__ float cf0[C_];
  __shared__ unsigned long long redL[TPB / 64];
  __shared__ unsigned long long bcK64;

  v2f z2[2][C_ / 2];
  float pn[2], dmin[2];
  const int p0 = g * SLICE + t;

  // ---- load this WG's 2 reg z-points per thread ----
#pragma unroll
  for (int j = 0; j < 2; ++j) {
    int p = p0 + j * TPB;
#pragma unroll
    for (int q = 0; q < C_ / 4; ++q) {
      float4 v = zb4[(size_t)p * 8 + q];
      z2[j][2 * q + 0] = v2f{v.x, v.y};
      z2[j][2 * q + 1] = v2f{v.z, v.w};
    }
    pn[j] = nrm[p];
    dmin[j] = 1e10f;
  }
  // ---- barycenter from partials (deterministic, same order as prior rounds) ----
  if (t < C_) {
    float s = 0.f;
#pragma unroll
    for (int c = 0; c < NCHUNK; ++c) s += partials[((size_t)b * NCHUNK + c) * C_ + t];
    cf0[t] = s * (1.f / (float)N_);
  }
  __syncthreads();

  // eval: bit-identical distance math to rounds 12/13 (same pk pairing + fold).
  auto eval = [&](const v2f (&csp)[C_ / 2], float curN,
                  bool update) -> unsigned long long {
    v2f a0 = {0.f, 0.f}, a1 = {0.f, 0.f};
#pragma unroll
    for (int i = 0; i < C_ / 2; ++i) {
      PKFMA(a0, z2[0][i], csp[i]);
      PKFMA(a1, z2[1][i], csp[i]);
    }
    float bv = -3e38f; int bi = 0;
    {
      float d = fmaf(-2.f, a0.x + a0.y, pn[0]) + curN;
      float v;
      if (update) { dmin[0] = fminf(dmin[0], d); v = dmin[0]; }
      else v = d;
      if (v > bv) { bv = v; bi = p0; }           // strict > keeps lowest index
    }
    {
      float d = fmaf(-2.f, a1.x + a1.y, pn[1]) + curN;
      float v;
      if (update) { dmin[1] = fminf(dmin[1], d); v = dmin[1]; }
      else v = d;
      if (v > bv) { bv = v; bi = p0 + TPB; }
    }
    unsigned long long k =
        ((unsigned long long)fmap(bv) << 12) | (unsigned)(4095 - bi);
    return wave_kmax(k);
  };

  // WG-local 4-wave reduce (redL filled + barrier done by caller), then RMW post.
  auto post = [&](int s) {
    if (t < 64) {
      unsigned long long k = redL[t & 3];
      k = kmax_dpp<0x111, 0xF>(k);
      k = kmax_dpp<0x112, 0xF>(k);
      unsigned lo = (unsigned)__builtin_amdgcn_readlane((int)(unsigned)k, 3);
      unsigned hi = (unsigned)__builtin_amdgcn_readlane((int)(unsigned)(k >> 32), 3);
      if (t == 0) {
        unsigned long long kwg = ((unsigned long long)hi << 32) | lo;
        __hip_atomic_fetch_max(&sK[s], kwg, __ATOMIC_RELAXED,
                               __HIP_MEMORY_SCOPE_AGENT);
        __hip_atomic_fetch_add(&sC[s], 1u, __ATOMIC_RELEASE,
                               __HIP_MEMORY_SCOPE_AGENT);
      }
    }
  };

  // ---- barycenter eval -> slot 0 (additive shift irrelevant for argmax) ----
  {
    v2f csp[C_ / 2];
#pragma unroll
    for (int i = 0; i < C_ / 2; ++i)
      csp[i] = v2f{rfl(cf0[2 * i]), rfl(cf0[2 * i + 1])};
    unsigned long long k = eval(csp, 0.f, false);
    if ((t & 63) == 63) redL[t >> 6] = k;
  }
  __syncthreads();
  post(0);

  // ---- main loop: selection s read from slot s; eval result -> slot s+1 ----
  for (int s = 0; s < M_; ++s) {
    if (t == 0) {
      while (__hip_atomic_load(&sC[s], __ATOMIC_ACQUIRE,
                               __HIP_MEMORY_SCOPE_AGENT) < (unsigned)NWG)
        __builtin_amdgcn_s_sleep(2);
      bcK64 = __hip_atomic_load(&sK[s], __ATOMIC_RELAXED,
                                __HIP_MEMORY_SCOPE_AGENT);
    }
    __syncthreads();
    unsigned long long kf = bcK64;
    int jsel = 4095 - (int)(kf & 4095ull);
    if (g == 0 && t == 0) idx_ws[run * M_ + s] = jsel;
    // owner kills its dmin slot (never re-select) — static indices
    if ((jsel >> 9) == g) {
      int loc = jsel & (SLICE - 1);
      if ((loc & (TPB - 1)) == t) {
        if (loc < TPB) dmin[0] = -3e38f;
        else dmin[1] = -3e38f;
      }
    }
    if (s == M_ - 1) break;
    // scalar-pipe fetch of selected point's 128B row + norm (uniform addr)
    const float* cfp = evb + (size_t)jsel * C_;
    const float* nrmp = nrm + jsel;
    v16f cs0, cs1; float curN;
    asm volatile(
        "s_load_dwordx16 %0, %3, 0\n\t"
        "s_load_dwordx16 %1, %3, 64\n\t"
        "s_load_dword %2, %4, 0\n\t"
        "s_waitcnt lgkmcnt(0)"
        : "=&s"(cs0), "=&s"(cs1), "=&s"(curN)
        : "s"(cfp), "s"(nrmp));
    v2f csp[C_ / 2];
#pragma unroll
    for (int i = 0; i < 8; ++i) {
      csp[i]     = v2f{cs0[2 * i], cs0[2 * i + 1]};
      csp[8 + i] = v2f{cs1[2 * i], cs1[2 * i + 1]};
    }
    unsigned long long kk = eval(csp, curN, true);
    if ((t & 63) == 63) redL[t >> 6] = kk;
    __syncthreads();
    post(s + 1);
  }
}

// ---------------- kernel 2: finalize (256 threads per batch) ----------------
// fps() returns selections in ASCENDING ORIGINAL-INDEX order (masked_select);
// rank-sort each run's indices before zipping along m (pairing matters).
// PRJ[0]=pe (ev-run pts @ Wpe), PRJ[1]=km (k-run pts @ Wk), PRJ[2]=vm (v-run @ Wv).
__global__ __launch_bounds__(256, 1) void finalize_kernel(
    const float* __restrict__ ev, const float* __restrict__ Wk,
    const float* __restrict__ Wv, const float* __restrict__ Wpe,
    const float* __restrict__ Wsa1, const float* __restrict__ Wsa2,
    const int* __restrict__ idx_ws, const float* __restrict__ partials,
    float* __restrict__ outvec_ws) {
  const int b = blockIdx.x;
  const int t = threadIdx.x;           // 256 threads = 4 waves
  const float* evb = ev + (size_t)b * N_ * C_;

  __shared__ float Wl[3][CN_][C_];        // 24 KB: Wpe, Wk, Wv
  __shared__ float W1l[CN_];
  __shared__ float W2l[C_][CN_ + 1];      // padded: conflict-free per-lane rows
  __shared__ int   lidx[3][M_], sidx[3][M_];
  __shared__ float XP[3][M_][C_];         // 24 KB selected rows
  __shared__ float PRJ[3][M_][CN_ + 1];   // padded
  __shared__ float sumx[C_], Pl[CN_], sl[M_], TP[4][CN_];

  // ---- stage weights ----
  {
    const float* Ws[3] = {Wpe, Wk, Wv};
#pragma unroll
    for (int r = 0; r < 3; ++r)
      for (int i = t; i < CN_ * C_ / 4; i += 256)
        ((float4*)&Wl[r][0][0])[i] = ((const float4*)Ws[r])[i];
    if (t < CN_) W1l[t] = Wsa1[t];
    for (int i = t; i < C_ * CN_; i += 256)
      W2l[i >> 6][i & 63] = Wsa2[i];      // scalar (padded dest not f4-aligned)
  }
  if (t < 192) {
    int r = t >> 6, mm = t & 63;
    lidx[r][mm] = idx_ws[(b * 3 + r) * M_ + mm];
  }
  if (t < C_) {
    float s = 0.f;
#pragma unroll
    for (int c = 0; c < NCHUNK; ++c) s += partials[((size_t)b * NCHUNK + c) * C_ + t];
    sumx[t] = s;
  }
  __syncthreads();
  if (t < 192) {       // parallel rank-sort: 3 runs × 64 slots
    int r = t >> 6, mm = t & 63;
    int my = lidx[r][mm];
    int rank = 0;
#pragma unroll
    for (int j = 0; j < M_; ++j)
      rank += (lidx[r][j] < my) || (lidx[r][j] == my && j < mm);
    sidx[r][rank] = my;
  }
  __syncthreads();
  // ---- stage selected rows: 192 rows × 8 quads ----
  for (int g = t; g < 3 * M_ * 8; g += 256) {
    int row = g >> 3, q = g & 7;
    int r = row >> 6, m = row & 63;
    int pi = sidx[r][m];
    *(float4*)&XP[r][m][q * 4] = ((const float4*)(evb + (size_t)pi * C_))[q];
  }
  __syncthreads();
  // ---- projections: wave r handles run r (lane = cn, W row in regs, x broadcast) ----
  {
    int w = t >> 6, cn = t & 63;
    if (w < 3) {
      float wr[C_];
#pragma unroll
      for (int q = 0; q < C_ / 4; ++q) {
        float4 v = *(const float4*)&Wl[w][cn][q * 4];
        wr[q * 4 + 0] = v.x; wr[q * 4 + 1] = v.y;
        wr[q * 4 + 2] = v.z; wr[q * 4 + 3] = v.w;
      }
      for (int m = 0; m < M_; ++m) {
        float a = 0.f;
#pragma unroll
        for (int q = 0; q < C_ / 4; ++q) {
          float4 x = *(const float4*)&XP[w][m][q * 4];   // wave-broadcast read
          a = fmaf(x.x, wr[q * 4 + 0], a);
          a = fmaf(x.y, wr[q * 4 + 1], a);
          a = fmaf(x.z, wr[q * 4 + 2], a);
          a = fmaf(x.w, wr[q * 4 + 3], a);
        }
        PRJ[w][m][cn] = a;
      }
    } else {
      // Pl[cn] = (Σ_n ev) @ Wpe^T
      float a = 0.f;
#pragma unroll
      for (int c = 0; c < C_; ++c) a = fmaf(sumx[c], Wl[0][cn][c], a);
      Pl[cn] = a;
    }
  }
  __syncthreads();
  // ---- logits + softmax: wave 0, lane m ----
  if (t < 64) {
    float cm = 0.f;
#pragma unroll 8
    for (int cn = 0; cn < CN_; ++cn)
      cm = fmaf(PRJ[1][t][cn] + PRJ[0][t][cn], W1l[cn], cm);
    float lg = -cm;
    float mx = lg;
#pragma unroll
    for (int off = 32; off; off >>= 1) mx = fmaxf(mx, __shfl_xor(mx, off));
    float e = expf(lg - mx);
    float ssum = e;
#pragma unroll
    for (int off = 32; off; off >>= 1) ssum += __shfl_xor(ssum, off);
    sl[t] = e / ssum;
  }
  __syncthreads();
  // ---- tvec partials: thread (cn = t&63, quarter h = t>>6) ----
  {
    int cn = t & 63, h = t >> 6;
    float a = 0.f;
#pragma unroll
    for (int i = 0; i < 16; ++i) {
      int mm = h * 16 + i;
      a = fmaf(sl[mm],
               fmaf((float)N_, PRJ[2][mm][cn], Pl[cn]) - (float)N_ * PRJ[0][mm][cn],
               a);
    }
    TP[h][cn] = a;
  }
  __syncthreads();
  if (t < C_) {
    float o = 0.f;
#pragma unroll 8
    for (int cn = 0; cn < CN_; ++cn) {
      float tv = TP[0][cn] + TP[1][cn] + TP[2][cn] + TP[3][cn];
      o = fmaf(tv, W2l[t][cn], o);
    }
    outvec_ws[b * C_ + t] = o;
  }
}

// ---------------- kernel 3: broadcast out[b][n][:] = outvec[b][:] ----------------
__global__ void bcast_kernel(const float* __restrict__ outvec_ws,
                             float4* __restrict__ out) {
  int i = blockIdx.x * 256 + threadIdx.x;   // < 4*4096*8
  int b = i >> 15;
  int j = i & 7;
  const float4* ov = (const float4*)outvec_ws;
  out[i] = ov[b * 8 + j];
}

extern "C" void kernel_launch(void* const* d_in, const int* in_sizes, int n_in,
                              void* d_out, int out_size, void* d_ws, size_t ws_size,
                              hipStream_t stream) {
  const float* ev   = (const float*)d_in[0];
  // d_in[1] = W_qs: provably unused (a_n cancels in softmax over m)
  const float* Wk   = (const float*)d_in[2];
  const float* Wv   = (const float*)d_in[3];
  const float* Wpe  = (const float*)d_in[4];
  const float* Wsa1 = (const float*)d_in[5];
  const float* Wsa2 = (const float*)d_in[6];
  float* out = (float*)d_out;

  // Layout kept within 4.5 MB (well under the 6.2 MB proven-good footprint).
  char* ws = (char*)d_ws;
  int*   idx    = (int*)ws;                     // 12*64*4        = 3072 B
  float* parts  = (float*)(ws + 3072);          // 4*16*32*4      = 8192 B
  float* outvec = (float*)(ws + 11264);         // 4*32*4         = 512 B
  unsigned long long* slotK =
      (unsigned long long*)(ws + 11776);        // 12*64*8        = 6144 B
  unsigned* slotC = (unsigned*)(ws + 17920);    // 12*64*4        = 3072 B
  float* nrm    = (float*)(ws + 20992);         // 12*4096*4      = 196608 B
  float* zall   = (float*)(ws + 217600);        // 8*4096*32*4    = 4194304 B

  // zero the sync slots EVERY launch (counts/keys start at 0; replay-safe)
  hipMemsetAsync(ws + 11776, 0, 9216, stream);
  norms_kernel   <<<dim3(192), dim3(NTPB), 0, stream>>>(ev, Wk, Wv, nrm, zall, parts);
  fps_kernel     <<<dim3(96),  dim3(TPB),  0, stream>>>(ev, nrm, zall, parts, idx,
                                                        slotK, slotC);
  finalize_kernel<<<dim3(4),   dim3(256),  0, stream>>>(ev, Wk, Wv, Wpe, Wsa1, Wsa2,
                                                        idx, parts, outvec);
  bcast_kernel   <<<dim3(512), dim3(256),  0, stream>>>(outvec, (float4*)out);
}

// Round 16
// 163.549 us; speedup vs baseline: 1.3556x; 1.3116x over previous
//
#include <hip/hip_runtime.h>

constexpr int N_ = 4096, C_ = 32, CN_ = 64, M_ = 64;
constexpr int TPB = 512;              // fps block: 8 waves, 2/SIMD, 256-reg budget
constexpr int RPT = 7, LPT = 1;       // reg / LDS points per thread
constexpr int NREG = RPT * TPB;       // 3584
constexpr int NLDS = N_ - NREG;       // 512
constexpr int NWAVES = TPB / 64;      // 8
constexpr int NTPB = 256;             // norms block
constexpr int NCHUNK = N_ / NTPB;     // 16

typedef float v2f  __attribute__((ext_vector_type(2)));
typedef float v16f __attribute__((ext_vector_type(16)));

// packed f32 FMA: acc.{lo,hi} += z.{lo,hi} * c.{lo,hi}; c is an SGPR pair
#define PKFMA(acc, zz, cc) \
  asm("v_pk_fma_f32 %0, %1, %2, %0" : "+v"(acc) : "v"(zz), "s"(cc))

// monotone f32 -> u32 map (total order preserved incl. negatives)
__device__ __forceinline__ unsigned fmap(float v) {
  unsigned u = __float_as_uint(v);
  u ^= (unsigned)((int)u >> 31) | 0x80000000u;
  return u;
}

// force a wave-uniform float into an SGPR
__device__ __forceinline__ float rfl(float v) {
  return __uint_as_float(__builtin_amdgcn_readfirstlane(__float_as_uint(v)));
}

// one DPP max-combine stage on a packed u64 key (VALU pipe — no LDS traffic).
template <int CTRL, int RM>
__device__ __forceinline__ unsigned long long kmax_dpp(unsigned long long k) {
  int lo = (int)(unsigned)k, hi = (int)(unsigned)(k >> 32);
  int plo = __builtin_amdgcn_update_dpp(lo, lo, CTRL, RM, 0xf, false);
  int phi = __builtin_amdgcn_update_dpp(hi, hi, CTRL, RM, 0xf, false);
  unsigned long long p =
      ((unsigned long long)(unsigned)phi << 32) | (unsigned)plo;
  return p > k ? p : k;
}

// full-wave max of packed key; lane 63 holds it.
__device__ __forceinline__ unsigned long long wave_kmax(unsigned long long k) {
  k = kmax_dpp<0x111, 0xF>(k);   // row_shr:1
  k = kmax_dpp<0x112, 0xF>(k);   // row_shr:2
  k = kmax_dpp<0x114, 0xF>(k);   // row_shr:4
  k = kmax_dpp<0x118, 0xF>(k);   // row_shr:8
  k = kmax_dpp<0x142, 0xA>(k);   // row_bcast:15 -> rows 1,3
  k = kmax_dpp<0x143, 0xC>(k);   // row_bcast:31 -> rows 2,3
  return k;
}

// ---------------- kernel 0: per-point z = G·x (f64 accum) + norms + Σx partials ----------------
// blk = (b*3+r)*16 + chunk ; r=0: G=I (z==x exactly -> not stored; fps reads ev),
// r=1: G=Wk^T Wk, r=2: G=Wv^T Wv
__global__ __attribute__((amdgpu_flat_work_group_size(NTPB, NTPB),
                          amdgpu_waves_per_eu(1, 4)))
void norms_kernel(
    const float* __restrict__ ev, const float* __restrict__ Wk,
    const float* __restrict__ Wv, float* __restrict__ nrm_all,
    float* __restrict__ zall, float* __restrict__ partials) {
  int blk = blockIdx.x;
  int chunk = blk & (NCHUNK - 1), br = blk >> 4;
  int r = br % 3, b = br / 3;
  int t = threadIdx.x;
  __shared__ float G[C_][C_ + 1];
  const float* W = (r == 1) ? Wk : Wv;
  for (int e = t; e < C_ * C_; e += NTPB) {
    int a = e >> 5, d = e & 31;
    float g;
    if (r == 0) {
      g = (a == d) ? 1.f : 0.f;
    } else {
      double acc = 0.0;
      for (int q = 0; q < CN_; ++q)
        acc += (double)W[q * C_ + a] * (double)W[q * C_ + d];
      g = (float)acc;
    }
    G[a][d] = g;
  }
  __syncthreads();
  int p = chunk * NTPB + t;
  const float4* row = (const float4*)(ev + ((size_t)b * N_ + p) * C_);
  float x[C_];
#pragma unroll
  for (int q = 0; q < C_ / 4; ++q) {
    float4 v = row[q];
    x[q * 4 + 0] = v.x; x[q * 4 + 1] = v.y; x[q * 4 + 2] = v.z; x[q * 4 + 3] = v.w;
  }
  double n = 0.0;
  float z[C_];
#pragma unroll
  for (int a = 0; a < C_; ++a) {
    double ta = 0.0;
#pragma unroll
    for (int d = 0; d < C_; ++d) ta += (double)G[a][d] * (double)x[d];
    z[a] = (float)ta;
    n += ta * (double)x[a];
  }
  nrm_all[(size_t)br * N_ + p] = (float)n;
  if (r != 0) {   // r==0: z == x bit-exactly; fps reads ev instead
    float4* zrow =
        (float4*)(zall + ((size_t)(2 * b + r - 1) * N_ + p) * C_);
#pragma unroll
    for (int q = 0; q < C_ / 4; ++q)
      zrow[q] = make_float4(z[q * 4 + 0], z[q * 4 + 1], z[q * 4 + 2], z[q * 4 + 3]);
  }

  if (r == 0) {   // deterministic per-chunk Σx partials (no atomics)
    __shared__ float msum[NTPB / 64][C_];
#pragma unroll
    for (int d = 0; d < C_; ++d) {
      float s = x[d];
#pragma unroll
      for (int off = 32; off; off >>= 1) s += __shfl_xor(s, off);
      if ((t & 63) == 0) msum[t >> 6][d] = s;
    }
    __syncthreads();
    if (t < C_)
      partials[((size_t)b * NCHUNK + chunk) * C_ + t] =
          msum[0][t] + msum[1][t] + msum[2][t] + msum[3][t];
  }
}

// ---------------- kernel 1: FPS — one block per (batch,run), z-metric ----------------
// d(i, sel) = n_i - 2 * z_i · x_sel + n_sel    (G symmetric: x_i·G·c = z_i·c)
// 512 threads, 2 waves/SIMD, waves_per_eu(2,2) -> 256-reg budget: 7 pts/thread
// in registers (z=224), only 512 pts in LDS -> 64 ds_read_b128/iter.
// Eval processes point PAIRS (2 live accs) to stay under 256 regs; per-point
// FP op order identical to rounds 12/15 (bit-identical selections).
__global__ __attribute__((amdgpu_flat_work_group_size(TPB, TPB),
                          amdgpu_waves_per_eu(2, 2)))
void fps_kernel(
    const float* __restrict__ ev, const float* __restrict__ nrm_all,
    const float* __restrict__ zall, const float* __restrict__ partials,
    int* __restrict__ idx_ws) {
  const int t = threadIdx.x;
  const int run = blockIdx.x;          // b*3 + r  (0..11)
  const int b = run / 3, r = run % 3;
  const float* evb = ev + (size_t)b * N_ * C_;
  const float* nrm = nrm_all + (size_t)run * N_;
  const float4* zb4 = (r == 0)
      ? (const float4*)evb
      : (const float4*)(zall + (size_t)(2 * b + r - 1) * N_ * C_);

  __shared__ float LP[C_ / 4][NLDS][4];   // [q][col][4] — conflict-free b128 (64 KB)
  __shared__ float cf0[C_];               // barycenter (round 0 only)
  __shared__ unsigned long long redK[2][NWAVES];

  v2f z2[RPT][C_ / 2];
  float pn[RPT], dmin[RPT];
  float nl, dminL;

  // ---- load reg z-points (as VGPR pairs for v_pk_fma_f32) ----
#pragma unroll
  for (int j = 0; j < RPT; ++j) {
    int p = j * TPB + t;
#pragma unroll
    for (int q = 0; q < C_ / 4; ++q) {
      float4 v = zb4[(size_t)p * 8 + q];
      z2[j][2 * q + 0] = v2f{v.x, v.y};
      z2[j][2 * q + 1] = v2f{v.z, v.w};
    }
    pn[j] = nrm[p];
    dmin[j] = 1e10f;
  }
  // ---- stage LDS z-point (1 per thread), [q][col] layout ----
  {
    int p = NREG + t;
#pragma unroll
    for (int q = 0; q < C_ / 4; ++q) {
      float4 v = zb4[(size_t)p * 8 + q];
      *(float4*)&LP[q][t][0] = v;
    }
    nl = nrm[p];
    dminL = 1e10f;
  }
  // ---- barycenter from partials (deterministic) ----
  if (t < C_) {
    float s = 0.f;
#pragma unroll
    for (int c = 0; c < NCHUNK; ++c) s += partials[((size_t)b * NCHUNK + c) * C_ + t];
    cf0[t] = s * (1.f / (float)N_);
  }
  __syncthreads();   // LP + cf0 ready

  // csp[] pairs are SGPR-resident. Returns wave-reduced packed key
  // (fmap(best_v) << 12) | (4095 - best_idx) via DPP (no LDS ops).
  auto eval = [&](const v2f (&csp)[C_ / 2], float curN,
                  bool update) -> unsigned long long {
    float bv = -3e38f; int bi = 0;
    // per-point distance + argmax update (FP order matches r12/r15)
    auto touch_reg = [&](int j, const v2f& a) {
      float d = fmaf(-2.f, a.x + a.y, pn[j]) + curN;
      float v;
      if (update) { dmin[j] = fminf(dmin[j], d); v = dmin[j]; }
      else v = d;
      if (v > bv) { bv = v; bi = j * TPB + t; }  // strict > keeps lowest index
    };
    // pair 0: LDS point + reg point 6 (issue ds_reads first; latency hides
    // under the three register-only pairs that follow)
    {
      v2f aL = {0.f, 0.f}, a6 = {0.f, 0.f};
#pragma unroll
      for (int q = 0; q < C_ / 4; ++q) {
        float4 l = *(const float4*)&LP[q][t][0];
        v2f l0 = {l.x, l.y}, l1 = {l.z, l.w};
        PKFMA(aL, l0, csp[2 * q + 0]);
        PKFMA(aL, l1, csp[2 * q + 1]);
        PKFMA(a6, z2[6][2 * q + 0], csp[2 * q + 0]);
        PKFMA(a6, z2[6][2 * q + 1], csp[2 * q + 1]);
      }
      touch_reg(6, a6);
      float d = fmaf(-2.f, aL.x + aL.y, nl) + curN;
      float v;
      if (update) { dminL = fminf(dminL, d); v = dminL; }
      else v = d;
      if (v > bv) { bv = v; bi = NREG + t; }
    }
    // reg pairs (0,1), (2,3), (4,5)
#pragma unroll
    for (int jp = 0; jp < 6; jp += 2) {
      v2f a0 = {0.f, 0.f}, a1 = {0.f, 0.f};
#pragma unroll
      for (int q = 0; q < C_ / 4; ++q) {
        PKFMA(a0, z2[jp][2 * q + 0], csp[2 * q + 0]);
        PKFMA(a0, z2[jp][2 * q + 1], csp[2 * q + 1]);
        PKFMA(a1, z2[jp + 1][2 * q + 0], csp[2 * q + 0]);
        PKFMA(a1, z2[jp + 1][2 * q + 1], csp[2 * q + 1]);
      }
      touch_reg(jp, a0);
      touch_reg(jp + 1, a1);
    }
    unsigned long long k =
        ((unsigned long long)fmap(bv) << 12) | (unsigned)(4095 - bi);
    return wave_kmax(k);
  };

  // ---- round 0: barycenter (additive shift irrelevant for argmax; no dmin update) ----
  {
    v2f csp[C_ / 2];
#pragma unroll
    for (int i = 0; i < C_ / 2; ++i)
      csp[i] = v2f{rfl(cf0[2 * i]), rfl(cf0[2 * i + 1])};
    unsigned long long k = eval(csp, 0.f, false);
    if ((t & 63) == 63) redK[0][t >> 6] = k;
  }
  __syncthreads();

  // ---- main loop: 1 barrier/iter; cross-wave reduce = 1 ds_read_b64 +
  // 3 DPP stages + readlane; centroid row fetched on the SCALAR pipe ----
  for (int it = 0; it < M_; ++it) {
    int rb = it & 1;
    unsigned long long k = redK[rb][t & (NWAVES - 1)];
    k = kmax_dpp<0x111, 0xF>(k);
    k = kmax_dpp<0x112, 0xF>(k);
    k = kmax_dpp<0x114, 0xF>(k);
    unsigned klo = (unsigned)__builtin_amdgcn_readlane((int)(unsigned)k, 7);
    int jsel = 4095 - (int)(klo & 4095u);          // SGPR-uniform
    if (t == 0) idx_ws[run * M_ + it] = jsel;
    // owner kills its dmin slot (never re-select) — static indices only
    if (jsel < NREG) {
      if ((jsel & (TPB - 1)) == t) {
        int j = jsel >> 9;
#pragma unroll
        for (int jj = 0; jj < RPT; ++jj)
          if (jj == j) dmin[jj] = -3e38f;
      }
    } else {
      if (jsel - NREG == t) dminL = -3e38f;
    }
    if (it == M_ - 1) break;
    // scalar-pipe fetch of the selected point's 128B row + norm (uniform addr)
    const float* cfp = evb + (size_t)jsel * C_;
    const float* nrmp = nrm + jsel;
    v16f cs0, cs1; float curN;
    asm volatile(
        "s_load_dwordx16 %0, %3, 0\n\t"
        "s_load_dwordx16 %1, %3, 64\n\t"
        "s_load_dword %2, %4, 0\n\t"
        "s_waitcnt lgkmcnt(0)"
        : "=&s"(cs0), "=&s"(cs1), "=&s"(curN)
        : "s"(cfp), "s"(nrmp));
    v2f csp[C_ / 2];
#pragma unroll
    for (int i = 0; i < 8; ++i) {
      csp[i]     = v2f{cs0[2 * i], cs0[2 * i + 1]};
      csp[8 + i] = v2f{cs1[2 * i], cs1[2 * i + 1]};
    }
    unsigned long long kk = eval(csp, curN, true);
    if ((t & 63) == 63) redK[rb ^ 1][t >> 6] = kk;
    __syncthreads();
  }
}

// ---------------- kernel 2: finalize (256 threads per batch) ----------------
// fps() returns selections in ASCENDING ORIGINAL-INDEX order (masked_select);
// rank-sort each run's indices before zipping along m (pairing matters).
// PRJ[0]=pe (ev-run pts @ Wpe), PRJ[1]=km (k-run pts @ Wk), PRJ[2]=vm (v-run @ Wv).
__global__ __launch_bounds__(256, 1) void finalize_kernel(
    const float* __restrict__ ev, const float* __restrict__ Wk,
    const float* __restrict__ Wv, const float* __restrict__ Wpe,
    const float* __restrict__ Wsa1, const float* __restrict__ Wsa2,
    const int* __restrict__ idx_ws, const float* __restrict__ partials,
    float* __restrict__ outvec_ws) {
  const int b = blockIdx.x;
  const int t = threadIdx.x;           // 256 threads = 4 waves
  const float* evb = ev + (size_t)b * N_ * C_;

  __shared__ float Wl[3][CN_][C_];        // 24 KB: Wpe, Wk, Wv
  __shared__ float W1l[CN_];
  __shared__ float W2l[C_][CN_ + 1];      // padded: conflict-free per-lane rows
  __shared__ int   lidx[3][M_], sidx[3][M_];
  __shared__ float XP[3][M_][C_];         // 24 KB selected rows
  __shared__ float PRJ[3][M_][CN_ + 1];   // padded
  __shared__ float sumx[C_], Pl[CN_], sl[M_], TP[4][CN_];

  // ---- stage weights ----
  {
    const float* Ws[3] = {Wpe, Wk, Wv};
#pragma unroll
    for (int r = 0; r < 3; ++r)
      for (int i = t; i < CN_ * C_ / 4; i += 256)
        ((float4*)&Wl[r][0][0])[i] = ((const float4*)Ws[r])[i];
    if (t < CN_) W1l[t] = Wsa1[t];
    for (int i = t; i < C_ * CN_; i += 256)
      W2l[i >> 6][i & 63] = Wsa2[i];      // scalar (padded dest not f4-aligned)
  }
  if (t < 192) {
    int r = t >> 6, mm = t & 63;
    lidx[r][mm] = idx_ws[(b * 3 + r) * M_ + mm];
  }
  if (t < C_) {
    float s = 0.f;
#pragma unroll
    for (int c = 0; c < NCHUNK; ++c) s += partials[((size_t)b * NCHUNK + c) * C_ + t];
    sumx[t] = s;
  }
  __syncthreads();
  if (t < 192) {       // parallel rank-sort: 3 runs × 64 slots
    int r = t >> 6, mm = t & 63;
    int my = lidx[r][mm];
    int rank = 0;
#pragma unroll
    for (int j = 0; j < M_; ++j)
      rank += (lidx[r][j] < my) || (lidx[r][j] == my && j < mm);
    sidx[r][rank] = my;
  }
  __syncthreads();
  // ---- stage selected rows: 192 rows × 8 quads ----
  for (int g = t; g < 3 * M_ * 8; g += 256) {
    int row = g >> 3, q = g & 7;
    int r = row >> 6, m = row & 63;
    int pi = sidx[r][m];
    *(float4*)&XP[r][m][q * 4] = ((const float4*)(evb + (size_t)pi * C_))[q];
  }
  __syncthreads();
  // ---- projections: wave r handles run r (lane = cn, W row in regs, x broadcast) ----
  {
    int w = t >> 6, cn = t & 63;
    if (w < 3) {
      float wr[C_];
#pragma unroll
      for (int q = 0; q < C_ / 4; ++q) {
        float4 v = *(const float4*)&Wl[w][cn][q * 4];
        wr[q * 4 + 0] = v.x; wr[q * 4 + 1] = v.y;
        wr[q * 4 + 2] = v.z; wr[q * 4 + 3] = v.w;
      }
      for (int m = 0; m < M_; ++m) {
        float a = 0.f;
#pragma unroll
        for (int q = 0; q < C_ / 4; ++q) {
          float4 x = *(const float4*)&XP[w][m][q * 4];   // wave-broadcast read
          a = fmaf(x.x, wr[q * 4 + 0], a);
          a = fmaf(x.y, wr[q * 4 + 1], a);
          a = fmaf(x.z, wr[q * 4 + 2], a);
          a = fmaf(x.w, wr[q * 4 + 3], a);
        }
        PRJ[w][m][cn] = a;
      }
    } else {
      // Pl[cn] = (Σ_n ev) @ Wpe^T
      float a = 0.f;
#pragma unroll
      for (int c = 0; c < C_; ++c) a = fmaf(sumx[c], Wl[0][cn][c], a);
      Pl[cn] = a;
    }
  }
  __syncthreads();
  // ---- logits + softmax: wave 0, lane m ----
  if (t < 64) {
    float cm = 0.f;
#pragma unroll 8
    for (int cn = 0; cn < CN_; ++cn)
      cm = fmaf(PRJ[1][t][cn] + PRJ[0][t][cn], W1l[cn], cm);
    float lg = -cm;
    float mx = lg;
#pragma unroll
    for (int off = 32; off; off >>= 1) mx = fmaxf(mx, __shfl_xor(mx, off));
    float e = expf(lg - mx);
    float ssum = e;
#pragma unroll
    for (int off = 32; off; off >>= 1) ssum += __shfl_xor(ssum, off);
    sl[t] = e / ssum;
  }
  __syncthreads();
  // ---- tvec partials: thread (cn = t&63, quarter h = t>>6) ----
  {
    int cn = t & 63, h = t >> 6;
    float a = 0.f;
#pragma unroll
    for (int i = 0; i < 16; ++i) {
      int mm = h * 16 + i;
      a = fmaf(sl[mm],
               fmaf((float)N_, PRJ[2][mm][cn], Pl[cn]) - (float)N_ * PRJ[0][mm][cn],
               a);
    }
    TP[h][cn] = a;
  }
  __syncthreads();
  if (t < C_) {
    float o = 0.f;
#pragma unroll 8
    for (int cn = 0; cn < CN_; ++cn) {
      float tv = TP[0][cn] + TP[1][cn] + TP[2][cn] + TP[3][cn];
      o = fmaf(tv, W2l[t][cn], o);
    }
    outvec_ws[b * C_ + t] = o;
  }
}

// ---------------- kernel 3: broadcast out[b][n][:] = outvec[b][:] ----------------
__global__ void bcast_kernel(const float* __restrict__ outvec_ws,
                             float4* __restrict__ out) {
  int i = blockIdx.x * 256 + threadIdx.x;   // < 4*4096*8
  int b = i >> 15;
  int j = i & 7;
  const float4* ov = (const float4*)outvec_ws;
  out[i] = ov[b * 8 + j];
}

extern "C" void kernel_launch(void* const* d_in, const int* in_sizes, int n_in,
                              void* d_out, int out_size, void* d_ws, size_t ws_size,
                              hipStream_t stream) {
  const float* ev   = (const float*)d_in[0];
  // d_in[1] = W_qs: provably unused (a_n cancels in softmax over m)
  const float* Wk   = (const float*)d_in[2];
  const float* Wv   = (const float*)d_in[3];
  const float* Wpe  = (const float*)d_in[4];
  const float* Wsa1 = (const float*)d_in[5];
  const float* Wsa2 = (const float*)d_in[6];
  float* out = (float*)d_out;

  // Layout within 4.4 MB (under the proven-good footprint).
  char* ws = (char*)d_ws;
  int*   idx    = (int*)ws;                     // 12*64*4        = 3072 B
  float* parts  = (float*)(ws + 3072);          // 4*16*32*4      = 8192 B
  float* outvec = (float*)(ws + 11264);         // 4*32*4         = 512 B
  float* nrm    = (float*)(ws + 11776);         // 12*4096*4      = 196608 B
  float* zall   = (float*)(ws + 208384);        // 8*4096*32*4    = 4194304 B

  norms_kernel   <<<dim3(192), dim3(NTPB), 0, stream>>>(ev, Wk, Wv, nrm, zall, parts);
  fps_kernel     <<<dim3(12),  dim3(TPB),  0, stream>>>(ev, nrm, zall, parts, idx);
  finalize_kernel<<<dim3(4),   dim3(256),  0, stream>>>(ev, Wk, Wv, Wpe, Wsa1, Wsa2,
                                                        idx, parts, outvec);
  bcast_kernel   <<<dim3(512), dim3(256),  0, stream>>>(outvec, (float4*)out);
}